// Round 1
// baseline (1207.260 us; speedup 1.0000x reference)
//
#include <hip/hip_runtime.h>

#define N_NODES 100000
#define N_EDGES 1200000
#define R_REL 3
#define RN (R_REL * N_NODES)   // 300000
#define RE (R_REL * N_EDGES)   // 3600000

__device__ __forceinline__ float bcast(float v, int l) {
  return __int_as_float(__builtin_amdgcn_readlane(__float_as_int(v), l));
}

// ---------------- CSR build ----------------
__global__ void k_zero(int* p, int n) {
  int i = blockIdx.x * 256 + threadIdx.x;
  if (i < n) p[i] = 0;
}

__global__ void k_count(const int* __restrict__ dst, int* __restrict__ deg) {
  int i = blockIdx.x * 256 + threadIdx.x;
  if (i < RE) {
    int r = i / N_EDGES;
    atomicAdd(&deg[r * N_NODES + dst[i]], 1);
  }
}

__global__ void k_scan1(const int* __restrict__ deg, int* __restrict__ P,
                        int* __restrict__ bsums) {
  __shared__ int sd[256];
  int t = threadIdx.x;
  int base = blockIdx.x * 2048 + t * 8;
  int v[8];
  int tot = 0;
#pragma unroll
  for (int q = 0; q < 8; q++) {
    v[q] = (base + q < RN) ? deg[base + q] : 0;
    tot += v[q];
  }
  sd[t] = tot;
  __syncthreads();
  for (int off = 1; off < 256; off <<= 1) {
    int x = (t >= off) ? sd[t - off] : 0;
    __syncthreads();
    sd[t] += x;
    __syncthreads();
  }
  int run = sd[t] - tot;  // exclusive prefix within chunk
#pragma unroll
  for (int q = 0; q < 8; q++) {
    if (base + q < RN) P[base + q] = run;
    run += v[q];
  }
  if (t == 255) bsums[blockIdx.x] = sd[255];
}

__global__ void k_scan2(const int* __restrict__ bsums, int* __restrict__ boffs, int nb) {
  __shared__ int sd[256];
  int t = threadIdx.x;
  int v = (t < nb) ? bsums[t] : 0;
  sd[t] = v;
  __syncthreads();
  for (int off = 1; off < 256; off <<= 1) {
    int x = (t >= off) ? sd[t - off] : 0;
    __syncthreads();
    sd[t] += x;
    __syncthreads();
  }
  if (t < nb) boffs[t] = sd[t] - v;
}

__global__ void k_scan3(int* __restrict__ P, int* __restrict__ cursor,
                        const int* __restrict__ boffs) {
  int i = blockIdx.x * 256 + threadIdx.x;
  if (i < RN) {
    int p = P[i] + boffs[i >> 11];
    P[i] = p;
    cursor[i] = p;
  }
}

__global__ void k_scatter(const int* __restrict__ src, const int* __restrict__ dst,
                          int* __restrict__ cursor, int* __restrict__ ssrc) {
  int i = blockIdx.x * 256 + threadIdx.x;
  if (i < RE) {
    int r = i / N_EDGES;
    int p = atomicAdd(&cursor[r * N_NODES + dst[i]], 1);
    ssrc[p] = src[i];
  }
}

// ---------------- node transforms: hp_r = h@w_w[r]+w_b[r], es=tanh(2*(h@d_w+d_b)),
// asrc[r][n][head], adst[r][n][head] ----------------
__global__ __launch_bounds__(256) void k_node(
    const float* __restrict__ h, const float* __restrict__ d_w,
    const float* __restrict__ d_b, const float* __restrict__ w_w,
    const float* __restrict__ w_b, const float* __restrict__ atten_w,
    const float* __restrict__ atten_b, float* __restrict__ hp,
    float* __restrict__ es, float* __restrict__ asrc, float* __restrict__ adst) {
  __shared__ float sW[4 * 4096];  // 64 KB: d_w, w_w[0..2], layout [m][k*64+c]
  int tid = threadIdx.x;
  for (int idx = tid; idx < 4096; idx += 256) {
    sW[idx] = d_w[idx];
    sW[4096 + idx] = w_w[idx];
    sW[8192 + idx] = w_w[4096 + idx];
    sW[12288 + idx] = w_w[8192 + idx];
  }
  __syncthreads();
  int lane = tid & 63, wid = tid >> 6;
  int wave = blockIdx.x * 4 + wid, nw = gridDim.x * 4;
  int k16 = lane & 15, hgrp = lane >> 4;
  float dbv = d_b[lane];
  float wbv0 = w_b[lane], wbv1 = w_b[64 + lane], wbv2 = w_b[128 + lane];
  float wa0[3], wa1[3], wa2[3], ab[3];
#pragma unroll
  for (int r = 0; r < 3; r++) {
    wa0[r] = atten_w[r * 48 + k16];
    wa1[r] = atten_w[r * 48 + 16 + k16];
    wa2[r] = atten_w[r * 48 + 32 + k16];
    ab[r] = atten_b[r];
  }
  for (int g = wave; g < N_NODES / 8; g += nw) {
    int n0 = g * 8;
    float hr[8];
#pragma unroll
    for (int i = 0; i < 8; i++) hr[i] = h[(n0 + i) * 64 + lane];
    float acc[8][4];
#pragma unroll
    for (int i = 0; i < 8; i++) {
      acc[i][0] = dbv; acc[i][1] = wbv0; acc[i][2] = wbv1; acc[i][3] = wbv2;
    }
#pragma unroll 4
    for (int k = 0; k < 64; k++) {
      float w0 = sW[k * 64 + lane];
      float w1 = sW[4096 + k * 64 + lane];
      float w2 = sW[8192 + k * 64 + lane];
      float w3 = sW[12288 + k * 64 + lane];
#pragma unroll
      for (int i = 0; i < 8; i++) {
        float a = bcast(hr[i], k);
        acc[i][0] += a * w0; acc[i][1] += a * w1;
        acc[i][2] += a * w2; acc[i][3] += a * w3;
      }
    }
#pragma unroll
    for (int i = 0; i < 8; i++) {
      int n = n0 + i;
      float esv = tanhf(2.f * acc[i][0]);
      es[n * 64 + lane] = esv;
#pragma unroll
      for (int r = 0; r < 3; r++) {
        float hpv = acc[i][1 + r];
        hp[(r * N_NODES + n) * 64 + lane] = hpv;
        float cs = hpv * wa0[r] + esv * wa2[r];
        float cd = hpv * wa1[r];
#pragma unroll
        for (int m = 1; m < 16; m <<= 1) {
          cs += __shfl_xor(cs, m);
          cd += __shfl_xor(cd, m);
        }
        if (k16 == 0) {
          asrc[(r * N_NODES + n) * 4 + hgrp] = cs + ab[r];
          adst[(r * N_NODES + n) * 4 + hgrp] = cd;
        }
      }
    }
  }
}

// ---------------- fused: per-dst softmax-aggregate + gate + final linear ----------------
__global__ __launch_bounds__(512) void k_fused(
    const float* __restrict__ hp, const float* __restrict__ es,
    const float* __restrict__ asrc, const float* __restrict__ adst,
    const int* __restrict__ P, const int* __restrict__ ssrc,
    const float* __restrict__ beta, const float* __restrict__ lin_w,
    const float* __restrict__ lin_b, float* __restrict__ out) {
  __shared__ __align__(16) float sLW[64 * 196];  // transposed lin_w: [c][j], stride 196
  int tid = threadIdx.x;
  for (int idx = tid; idx < 192 * 64; idx += 512) {
    int j = idx >> 6, c = idx & 63;
    sLW[c * 196 + j] = lin_w[idx];
  }
  __syncthreads();
  int lane = tid & 63, wid = tid >> 6;
  int g = blockIdx.x * 8 + wid;  // 4 nodes per wave
  int hgrp = lane >> 4;
  float y0 = lin_b[lane];
  float y[4] = {y0, y0, y0, y0};
  for (int r = 0; r < 3; r++) {
    float hr[4];
    float b0 = beta[r * 128 + lane], b1 = beta[r * 128 + 64 + lane];
#pragma unroll
    for (int i = 0; i < 4; i++) {
      int n = g * 4 + i;
      int idxrn = r * N_NODES + n;
      int beg = P[idxrn];
      int end = (idxrn + 1 < RN) ? P[idxrn + 1] : RE;
      float adh = adst[idxrn * 4 + hgrp];
      float oacc = 0.f, eacc = 0.f, dsum = 0.f;
      for (int e = beg; e < end; ++e) {
        int s = ssrc[e];
        float a = asrc[(r * N_NODES + s) * 4 + hgrp] + adh;
        a = a >= 0.f ? a : 0.01f * a;
        float ex = __expf(a);
        float hv = hp[(r * N_NODES + s) * 64 + lane];
        float ev = es[s * 64 + lane];
        oacc += ex * hv;
        eacc += ev;
        dsum += ex;
      }
      float ov = oacc / fmaxf(dsum, 1e-20f);
      float em = eacc / fmaxf((float)(end - beg), 1.f);
      float gc = em * b0 + ov * b1;
#pragma unroll
      for (int m = 1; m < 64; m <<= 1) gc += __shfl_xor(gc, m);
      float gt = 1.f / (1.f + __expf(-gc));
      float hpv = hp[idxrn * 64 + lane];
      hr[i] = gt * ov + (1.f - gt) * hpv;
    }
    const float* wrow = &sLW[lane * 196 + r * 64];
#pragma unroll
    for (int j4 = 0; j4 < 64; j4 += 4) {
      float4 wv = *reinterpret_cast<const float4*>(wrow + j4);
#pragma unroll
      for (int i = 0; i < 4; i++) {
        y[i] += bcast(hr[i], j4) * wv.x + bcast(hr[i], j4 + 1) * wv.y +
                bcast(hr[i], j4 + 2) * wv.z + bcast(hr[i], j4 + 3) * wv.w;
      }
    }
  }
#pragma unroll
  for (int i = 0; i < 4; i++) out[(g * 4 + i) * 64 + lane] = y[i];
}

extern "C" void kernel_launch(void* const* d_in, const int* in_sizes, int n_in,
                              void* d_out, int out_size, void* d_ws, size_t ws_size,
                              hipStream_t stream) {
  const float* h = (const float*)d_in[0];
  const int* src = (const int*)d_in[1];
  const int* dst = (const int*)d_in[2];
  const float* d_w = (const float*)d_in[3];
  const float* d_b = (const float*)d_in[4];
  const float* w_w = (const float*)d_in[5];
  const float* w_b = (const float*)d_in[6];
  const float* atten_w = (const float*)d_in[7];
  const float* atten_b = (const float*)d_in[8];
  const float* beta = (const float*)d_in[9];
  const float* lin_w = (const float*)d_in[10];
  const float* lin_b = (const float*)d_in[11];
  float* out = (float*)d_out;

  float* ws = (float*)d_ws;
  float* hp = ws;                                    // R*N*64
  float* es = hp + (size_t)R_REL * N_NODES * 64;     // N*64
  float* asrc = es + (size_t)N_NODES * 64;           // R*N*4
  float* adst = asrc + (size_t)R_REL * N_NODES * 4;  // R*N*4
  int* deg = (int*)(adst + (size_t)R_REL * N_NODES * 4);  // RN
  int* P = deg + RN;                                 // RN
  int* cursor = P + RN;                              // RN
  int* bsums = cursor + RN;                          // 256
  int* boffs = bsums + 256;                          // 256
  int* ssrc = boffs + 256;                           // RE

  int nb = (RN + 2047) / 2048;
  k_zero<<<(RN + 255) / 256, 256, 0, stream>>>(deg, RN);
  k_count<<<(RE + 255) / 256, 256, 0, stream>>>(dst, deg);
  k_scan1<<<nb, 256, 0, stream>>>(deg, P, bsums);
  k_scan2<<<1, 256, 0, stream>>>(bsums, boffs, nb);
  k_scan3<<<(RN + 255) / 256, 256, 0, stream>>>(P, cursor, boffs);
  k_scatter<<<(RE + 255) / 256, 256, 0, stream>>>(src, dst, cursor, ssrc);
  k_node<<<1024, 256, 0, stream>>>(h, d_w, d_b, w_w, w_b, atten_w, atten_b, hp, es,
                                   asrc, adst);
  k_fused<<<N_NODES / 32, 512, 0, stream>>>(hp, es, asrc, adst, P, ssrc, beta, lin_w,
                                            lin_b, out);
}